// Round 4
// baseline (672.778 us; speedup 1.0000x reference)
//
#include <hip/hip_runtime.h>
#include <stdint.h>

#define DIM_TIME 100
#define DQ 228
#define DKV 356
#define KPAD 384
#define NB 256
#define BM 32
#define BK 32
#define NCHUNK 12
#define A_STRIDE 392   // bf16 elems
#define C_STRIDE 264   // bf16 elems, epilogue staging

typedef short v8s __attribute__((ext_vector_type(8)));
typedef float v4f __attribute__((ext_vector_type(4)));

__device__ __forceinline__ unsigned short bf16_bits(float f) {
    union { float f; uint32_t u; } c; c.f = f;
    uint32_t u = c.u;
    uint32_t r = (u + 0x7FFFu + ((u >> 16) & 1u)) >> 16;
    return (unsigned short)r;
}
__device__ __forceinline__ float bf16_lo(uint32_t u) {
    union { uint32_t u; float f; } c; c.u = u << 16; return c.f;
}
__device__ __forceinline__ float bf16_hi(uint32_t u) {
    union { uint32_t u; float f; } c; c.u = u & 0xFFFF0000u; return c.f;
}

// ---- prep: Wt2[n][k] bf16, n in [0,256), k padded to 384 ----
__global__ void prep_wt2(const float* __restrict__ wk_w, const float* __restrict__ wv_w,
                         unsigned short* __restrict__ Wt2) {
    int n = blockIdx.x;
    int k = threadIdx.x;
    float v = 0.f;
    if (k < DKV) v = (n < 128) ? wk_w[n * DKV + k] : wv_w[(n - 128) * DKV + k];
    Wt2[n * KPAD + k] = bf16_bits(v);
}

__global__ void prep_wqt(const float* __restrict__ wq_w, float* __restrict__ Wqt) {
    int k = blockIdx.x, o = threadIdx.x;
    Wqt[k * 128 + o] = wq_w[o * DQ + k];
}

__global__ void prep_wot(const float* __restrict__ wout_w, float* __restrict__ Wot) {
    int k = blockIdx.x, o = threadIdx.x;
    Wot[k * 128 + o] = wout_w[o * 256 + k];
}

__global__ void prep_cq(const float* __restrict__ wq_w, const float* __restrict__ wq_b,
                        const float* __restrict__ time_b, float* __restrict__ cq) {
    int o = threadIdx.x;
    float s = wq_b[o];
    for (int t = 0; t < DIM_TIME; ++t)
        s += cosf(time_b[t]) * wq_w[o * DQ + 128 + t];
    cq[o] = s;
}

// ---- Qd: 4 waves x 8 rows, o = 2*lane column mapping, float2 weight loads ----
__global__ __launch_bounds__(256) void qd_kernel(
        const float* __restrict__ src_feat, const int* __restrict__ src_idx,
        const float* __restrict__ Wqt, const float* __restrict__ cq,
        float* __restrict__ Qd, int D) {
    __shared__ float q_s[32][128];
    int lane = threadIdx.x & 63, wave = threadIdx.x >> 6;
    int r0 = wave * 8;
    int d0 = blockIdx.x * 32 + r0;
    #pragma unroll
    for (int i = 0; i < 8; ++i) {
        int d = d0 + i;
        float v0 = 0.f, v1 = 0.f;
        if (d < D) {
            const float* p = src_feat + (size_t)src_idx[d] * 128;
            v0 = p[lane]; v1 = p[lane + 64];
        }
        q_s[r0 + i][lane] = v0; q_s[r0 + i][lane + 64] = v1;
    }
    float2 c2 = *(const float2*)(cq + 2 * lane);
    float acc0[8], acc1[8];
    #pragma unroll
    for (int i = 0; i < 8; ++i) { acc0[i] = c2.x; acc1[i] = c2.y; }
    #pragma unroll 8
    for (int k = 0; k < 128; ++k) {
        float2 w = *(const float2*)(Wqt + k * 128 + 2 * lane);
        #pragma unroll
        for (int i = 0; i < 8; ++i) {
            float a = q_s[r0 + i][k];
            acc0[i] += a * w.x; acc1[i] += a * w.y;
        }
    }
    #pragma unroll
    for (int i = 0; i < 8; ++i) {
        int d = d0 + i;
        if (d < D)
            *(float2*)(Qd + (size_t)d * 128 + 2 * lane) = make_float2(acc0[i], acc1[i]);
    }
}

// ---- KV GEMM via MFMA: BM=32 for high occupancy ----
__global__ __launch_bounds__(256) void kv_mfma(
        const float* __restrict__ src_feat, const int* __restrict__ src_idx,
        const float* __restrict__ edge_f, const float* __restrict__ edge_dt,
        const float* __restrict__ time_w, const float* __restrict__ time_b,
        const unsigned short* __restrict__ Wt2,
        const float* __restrict__ wk_b, const float* __restrict__ wv_b,
        unsigned short* __restrict__ KVb, int D, int E) {
    __shared__ unsigned short A_s[BM * A_STRIDE];   // 25088 B
    int tid = threadIdx.x;
    int e0 = blockIdx.x * BM;
    int lane = tid & 63, wave = tid >> 6;
    int l15 = lane & 15, quad = lane >> 4;
    int wn = wave * 64;

    // ---- build A tile (bf16): 32 rows, 8 threads/row ----
    {
        int row = tid >> 3;          // 0..31
        int cb  = (tid & 7) * 4;     // float4-group base (0..28)
        int e = e0 + row;
        bool ok = (e < E);
        size_t nbase = ok ? (size_t)src_idx[D + e] * 128 : 0;
        #pragma unroll
        for (int i = 0; i < 4; ++i) {
            int c4 = cb + i;
            float4 v = ok ? *(const float4*)(src_feat + nbase + c4 * 4)
                          : make_float4(0.f, 0.f, 0.f, 0.f);
            ushort4 w;
            w.x = bf16_bits(v.x); w.y = bf16_bits(v.y);
            w.z = bf16_bits(v.z); w.w = bf16_bits(v.w);
            *(ushort4*)&A_s[row * A_STRIDE + c4 * 4] = w;
        }
        #pragma unroll
        for (int i = 0; i < 4; ++i) {
            int c4 = cb + i;
            float4 v = ok ? *(const float4*)(edge_f + (size_t)e * 128 + c4 * 4)
                          : make_float4(0.f, 0.f, 0.f, 0.f);
            ushort4 w;
            w.x = bf16_bits(v.x); w.y = bf16_bits(v.y);
            w.z = bf16_bits(v.z); w.w = bf16_bits(v.w);
            *(ushort4*)&A_s[row * A_STRIDE + 128 + c4 * 4] = w;
        }
    }
    {   // time cols 256..383
        int c = tid & 127;
        int rbase = tid >> 7;        // 0 or 1
        bool vc = (c < DIM_TIME);
        float tw = vc ? time_w[c] : 0.f;
        float tb = vc ? time_b[c] : 0.f;
        #pragma unroll
        for (int i = 0; i < 16; ++i) {
            int row = i * 2 + rbase;
            int e = e0 + row;
            float v = 0.f;
            if (vc && e < E) v = __cosf(edge_dt[e] * tw + tb);
            A_s[row * A_STRIDE + 256 + c] = bf16_bits(v);
        }
    }
    __syncthreads();

    v4f acc[2][4];
    #pragma unroll
    for (int mf = 0; mf < 2; ++mf)
        #pragma unroll
        for (int nf = 0; nf < 4; ++nf)
            acc[mf][nf] = (v4f)(0.f);

    const unsigned short* wp = Wt2 + (size_t)(wn + l15) * KPAD + quad * 8;
    const unsigned short* ap = A_s + l15 * A_STRIDE + quad * 8;

    v8s bcur[4], acur[2];
    #pragma unroll
    for (int nf = 0; nf < 4; ++nf) bcur[nf] = *(const v8s*)(wp + nf * 16 * KPAD);
    #pragma unroll
    for (int mf = 0; mf < 2; ++mf) acur[mf] = *(const v8s*)(ap + mf * 16 * A_STRIDE);

    #pragma unroll 2
    for (int ch = 0; ch < NCHUNK; ++ch) {
        int k2 = (ch + 1 < NCHUNK) ? (ch + 1) * BK : 0;
        v8s bn[4], an[2];
        #pragma unroll
        for (int nf = 0; nf < 4; ++nf) bn[nf] = *(const v8s*)(wp + nf * 16 * KPAD + k2);
        #pragma unroll
        for (int mf = 0; mf < 2; ++mf) an[mf] = *(const v8s*)(ap + mf * 16 * A_STRIDE + k2);
        #pragma unroll
        for (int mf = 0; mf < 2; ++mf)
            #pragma unroll
            for (int nf = 0; nf < 4; ++nf)
                acc[mf][nf] = __builtin_amdgcn_mfma_f32_16x16x32_bf16(
                                  acur[mf], bcur[nf], acc[mf][nf], 0, 0, 0);
        #pragma unroll
        for (int nf = 0; nf < 4; ++nf) bcur[nf] = bn[nf];
        #pragma unroll
        for (int mf = 0; mf < 2; ++mf) acur[mf] = an[mf];
    }

    // ---- epilogue: stage C in LDS (reuse A_s), then linear stores ----
    __syncthreads();
    #pragma unroll
    for (int nf = 0; nf < 4; ++nf) {
        int n = wn + nf * 16 + l15;
        float bias = (n < 128) ? wk_b[n] : wv_b[n - 128];
        #pragma unroll
        for (int mf = 0; mf < 2; ++mf)
            #pragma unroll
            for (int r = 0; r < 4; ++r)
                A_s[(mf * 16 + quad * 4 + r) * C_STRIDE + n] =
                    bf16_bits(acc[mf][nf][r] + bias);
    }
    __syncthreads();
    #pragma unroll
    for (int j = 0; j < 4; ++j) {
        int c = j * 256 + tid;          // 0..1023 chunks of 8 ushorts
        int row = c >> 5;
        int col = (c & 31) * 8;
        if (e0 + row < E) {
            v8s v = *(const v8s*)&A_s[row * C_STRIDE + col];
            *(v8s*)&KVb[(size_t)(e0 + row) * NB + col] = v;
        }
    }
}

// ---- segment offsets (edge_dst sorted) ----
__global__ void seg_offsets(const int* __restrict__ edge_dst, int* __restrict__ start,
                            int D, int E) {
    int d = blockIdx.x * blockDim.x + threadIdx.x;
    if (d > D) return;
    int lo = 0, hi = E;
    while (lo < hi) {
        int mid = (lo + hi) >> 1;
        if (edge_dst[mid] < d) lo = mid + 1; else hi = mid;
    }
    start[d] = lo;
}

// ---- attention: wave per 4 dsts, strip-4 edge prefetch, 2 outputs/lane ----
__global__ __launch_bounds__(256) void attn_kernel(
        const float* __restrict__ Qd, const unsigned short* __restrict__ KVb,
        const int* __restrict__ start, float* __restrict__ h, int D) {
    int lane = threadIdx.x & 63, wave = threadIdx.x >> 6;
    int dbase = blockIdx.x * 16 + wave * 4;
    for (int i = 0; i < 4; ++i) {
        int d = dbase + i;
        if (d >= D) break;
        float2 q = *(const float2*)(Qd + (size_t)d * 128 + lane * 2);
        int s0 = start[d], s1 = start[d + 1];
        float m = -INFINITY, l = 0.f, a0 = 0.f, a1 = 0.f;
        for (int e = s0; e < s1; e += 4) {
            int n = s1 - e; if (n > 4) n = 4;
            uint32_t ku[4], vu[4];
            #pragma unroll
            for (int j = 0; j < 4; ++j) {
                if (j < n) {
                    const unsigned short* kv = KVb + (size_t)(e + j) * 256 + lane * 2;
                    ku[j] = *(const uint32_t*)kv;
                    vu[j] = *(const uint32_t*)(kv + 128);
                }
            }
            for (int j = 0; j < n; ++j) {
                float qk = q.x * bf16_lo(ku[j]) + q.y * bf16_hi(ku[j]);
                qk += __shfl_xor(qk, 4, 8);
                qk += __shfl_xor(qk, 2, 8);
                qk += __shfl_xor(qk, 1, 8);
                float s = qk > 0.f ? qk : 0.2f * qk;   // leaky_relu(., 0.2)
                float nm = fmaxf(m, s);
                float sc = __expf(m - nm);
                float p  = __expf(s - nm);
                l  = l  * sc + p;
                a0 = a0 * sc + p * bf16_lo(vu[j]);
                a1 = a1 * sc + p * bf16_hi(vu[j]);
                m = nm;
            }
        }
        float inv = (l > 0.f) ? 1.f / l : 0.f;
        *(float2*)(h + (size_t)d * 128 + lane * 2) = make_float2(a0 * inv, a1 * inv);
    }
}

// ---- out = LN(relu([h, q_data] @ wout^T + b)) : o = 2*lane mapping ----
__global__ __launch_bounds__(256) void out_kernel(
        const float* __restrict__ h, const float* __restrict__ src_feat,
        const int* __restrict__ src_idx, const float* __restrict__ Wot,
        const float* __restrict__ wout_b, const float* __restrict__ ln_g,
        const float* __restrict__ ln_b, float* __restrict__ out, int D) {
    __shared__ float in_s[32][256];
    int lane = threadIdx.x & 63, wave = threadIdx.x >> 6;
    int r0 = wave * 8;
    int d0 = blockIdx.x * 32 + r0;
    #pragma unroll
    for (int i = 0; i < 8; ++i) {
        int d = d0 + i;
        float a0 = 0.f, a1 = 0.f, b0 = 0.f, b1 = 0.f;
        if (d < D) {
            const float* ph = h + (size_t)d * 128;
            a0 = ph[lane]; a1 = ph[lane + 64];
            const float* pf = src_feat + (size_t)src_idx[d] * 128;
            b0 = pf[lane]; b1 = pf[lane + 64];
        }
        in_s[r0 + i][lane] = a0; in_s[r0 + i][lane + 64] = a1;
        in_s[r0 + i][128 + lane] = b0; in_s[r0 + i][192 + lane] = b1;
    }
    float2 bb = *(const float2*)(wout_b + 2 * lane);
    float acc0[8], acc1[8];
    #pragma unroll
    for (int i = 0; i < 8; ++i) { acc0[i] = bb.x; acc1[i] = bb.y; }
    #pragma unroll 8
    for (int k = 0; k < 256; ++k) {
        float2 w = *(const float2*)(Wot + k * 128 + 2 * lane);
        #pragma unroll
        for (int i = 0; i < 8; ++i) {
            float a = in_s[r0 + i][k];
            acc0[i] += a * w.x; acc1[i] += a * w.y;
        }
    }
    float2 g = *(const float2*)(ln_g + 2 * lane);
    float2 lb = *(const float2*)(ln_b + 2 * lane);
    #pragma unroll
    for (int i = 0; i < 8; ++i) {
        float v0 = fmaxf(acc0[i], 0.f), v1 = fmaxf(acc1[i], 0.f);
        float s1 = v0 + v1, s2 = v0 * v0 + v1 * v1;
        #pragma unroll
        for (int off = 32; off; off >>= 1) {
            s1 += __shfl_xor(s1, off);
            s2 += __shfl_xor(s2, off);
        }
        float mu  = s1 * (1.f / 128.f);
        float var = s2 * (1.f / 128.f) - mu * mu;
        float rs  = rsqrtf(var + 1e-5f);
        int d = d0 + i;
        if (d < D)
            *(float2*)(out + (size_t)d * 128 + 2 * lane) =
                make_float2((v0 - mu) * rs * g.x + lb.x, (v1 - mu) * rs * g.y + lb.y);
    }
}

extern "C" void kernel_launch(void* const* d_in, const int* in_sizes, int n_in,
                              void* d_out, int out_size, void* d_ws, size_t ws_size,
                              hipStream_t stream) {
    const float* src_feat = (const float*)d_in[0];
    const float* edge_f   = (const float*)d_in[1];
    const float* edge_dt  = (const float*)d_in[2];
    const float* time_w   = (const float*)d_in[3];
    const float* time_b   = (const float*)d_in[4];
    const float* wq_w     = (const float*)d_in[5];
    const float* wq_b     = (const float*)d_in[6];
    const float* wk_w     = (const float*)d_in[7];
    const float* wk_b     = (const float*)d_in[8];
    const float* wv_w     = (const float*)d_in[9];
    const float* wv_b     = (const float*)d_in[10];
    const float* wout_w   = (const float*)d_in[11];
    const float* wout_b   = (const float*)d_in[12];
    const float* ln_g     = (const float*)d_in[13];
    const float* ln_b     = (const float*)d_in[14];
    const int*   src_idx  = (const int*)d_in[15];
    const int*   edge_dst = (const int*)d_in[16];

    int DE = in_sizes[0] / 128;
    int E  = in_sizes[1] / 128;
    int D  = DE - E;

    char* ws = (char*)d_ws;
    size_t off = 0;
    auto alloc = [&](size_t bytes) {
        void* p = ws + off;
        off = (off + bytes + 511) & ~(size_t)511;
        return p;
    };
    unsigned short* Wt2   = (unsigned short*)alloc((size_t)NB * KPAD * 2);
    float*          Wqt   = (float*)alloc(128 * 128 * 4);
    float*          Wot   = (float*)alloc(256 * 128 * 4);
    float*          cq    = (float*)alloc(128 * 4);
    float*          Qd    = (float*)alloc((size_t)D * 128 * 4);
    unsigned short* KVb   = (unsigned short*)alloc((size_t)E * 256 * 2);
    float*          hb    = (float*)alloc((size_t)D * 128 * 4);
    int*            start = (int*)alloc((size_t)(D + 1) * 4);

    hipLaunchKernelGGL(prep_wt2, dim3(NB), dim3(KPAD), 0, stream, wk_w, wv_w, Wt2);
    hipLaunchKernelGGL(prep_wqt, dim3(128), dim3(128), 0, stream, wq_w, Wqt);
    hipLaunchKernelGGL(prep_wot, dim3(256), dim3(128), 0, stream, wout_w, Wot);
    hipLaunchKernelGGL(prep_cq, dim3(1), dim3(128), 0, stream, wq_w, wq_b, time_b, cq);
    hipLaunchKernelGGL(qd_kernel, dim3((D + 31) / 32), dim3(256), 0, stream,
                       src_feat, src_idx, Wqt, cq, Qd, D);
    hipLaunchKernelGGL(kv_mfma, dim3((E + BM - 1) / BM), dim3(256), 0, stream,
                       src_feat, src_idx, edge_f, edge_dt, time_w, time_b,
                       Wt2, wk_b, wv_b, KVb, D, E);
    hipLaunchKernelGGL(seg_offsets, dim3((D + 1 + 255) / 256), dim3(256), 0, stream,
                       edge_dst, start, D, E);
    hipLaunchKernelGGL(attn_kernel, dim3((D + 15) / 16), dim3(256), 0, stream,
                       Qd, KVb, start, hb, D);
    hipLaunchKernelGGL(out_kernel, dim3((D + 31) / 32), dim3(256), 0, stream,
                       hb, src_feat, src_idx, Wot, wout_b, ln_g, ln_b, (float*)d_out, D);
}

// Round 5
// 613.076 us; speedup vs baseline: 1.0974x; 1.0974x over previous
//
#include <hip/hip_runtime.h>
#include <stdint.h>

#define DIM_TIME 100
#define DQ 228
#define DKV 356
#define KPAD 384
#define NB 256
#define BM 32
#define BK 32
#define NCHUNK 12
#define A_STRIDE 392   // bf16 elems (784 B -> 196 dw, %32==4: 2-way, free)
#define BSTR 36        // kv B row stride (72 B -> 18 dw, odd*2: conflict-lite)
#define C_STRIDE 264   // epilogue staging

#define QD_ASTR 136
#define QD_BSTR 136
#define OUT_ASTR 264
#define OUT_CSTR 132

typedef short v8s __attribute__((ext_vector_type(8)));
typedef float v4f __attribute__((ext_vector_type(4)));

__device__ __forceinline__ unsigned short bf16_bits(float f) {
    union { float f; uint32_t u; } c; c.f = f;
    uint32_t u = c.u;
    uint32_t r = (u + 0x7FFFu + ((u >> 16) & 1u)) >> 16;
    return (unsigned short)r;
}
__device__ __forceinline__ float bf16_lo(uint32_t u) {
    union { uint32_t u; float f; } c; c.u = u << 16; return c.f;
}
__device__ __forceinline__ float bf16_hi(uint32_t u) {
    union { uint32_t u; float f; } c; c.u = u & 0xFFFF0000u; return c.f;
}
__device__ __forceinline__ v8s cvt8(float4 a, float4 b) {
    union { v8s v; unsigned short u[8]; } r;
    r.u[0] = bf16_bits(a.x); r.u[1] = bf16_bits(a.y);
    r.u[2] = bf16_bits(a.z); r.u[3] = bf16_bits(a.w);
    r.u[4] = bf16_bits(b.x); r.u[5] = bf16_bits(b.y);
    r.u[6] = bf16_bits(b.z); r.u[7] = bf16_bits(b.w);
    return r.v;
}

// ---- preps ----
__global__ void prep_wt2(const float* __restrict__ wk_w, const float* __restrict__ wv_w,
                         unsigned short* __restrict__ Wt2) {
    int n = blockIdx.x, k = threadIdx.x;
    float v = 0.f;
    if (k < DKV) v = (n < 128) ? wk_w[n * DKV + k] : wv_w[(n - 128) * DKV + k];
    Wt2[n * KPAD + k] = bf16_bits(v);
}
__global__ void prep_wqb(const float* __restrict__ wq_w, unsigned short* __restrict__ Wqb) {
    int n = blockIdx.x, k = threadIdx.x;  // 128 x 128
    Wqb[n * 128 + k] = bf16_bits(wq_w[n * DQ + k]);
}
__global__ void prep_wob(const float* __restrict__ wout_w, unsigned short* __restrict__ Wob) {
    int n = blockIdx.x, k = threadIdx.x;  // 128 x 256
    Wob[n * 256 + k] = bf16_bits(wout_w[n * 256 + k]);
}
__global__ void prep_cq(const float* __restrict__ wq_w, const float* __restrict__ wq_b,
                        const float* __restrict__ time_b, float* __restrict__ cq) {
    int o = threadIdx.x;
    float s = wq_b[o];
    for (int t = 0; t < DIM_TIME; ++t)
        s += cosf(time_b[t]) * wq_w[o * DQ + 128 + t];
    cq[o] = s;
}

// ---- Qd via MFMA: C-tile 32x128, B fully LDS-staged ----
__global__ __launch_bounds__(256) void qd_mfma(
        const float* __restrict__ src_feat, const int* __restrict__ src_idx,
        const unsigned short* __restrict__ Wqb, const float* __restrict__ cq,
        float* __restrict__ Qd, int D) {
    __shared__ unsigned short A_s[32 * QD_ASTR];
    __shared__ unsigned short B_s[128 * QD_BSTR];
    int tid = threadIdx.x;
    int lane = tid & 63, wave = tid >> 6;
    int l15 = lane & 15, quad = lane >> 4;
    int wn = wave * 32;
    int d0 = blockIdx.x * 32;

    {   // stage B (128 rows x 128 k), 4 threads/row, 2 rounds
        int row = tid >> 2, sub = tid & 3;
        #pragma unroll
        for (int j = 0; j < 2; ++j) {
            int r = row + j * 64;
            #pragma unroll
            for (int t = 0; t < 4; ++t) {
                v8s v = *(const v8s*)(Wqb + (size_t)r * 128 + sub * 32 + t * 8);
                *(v8s*)&B_s[r * QD_BSTR + sub * 32 + t * 8] = v;
            }
        }
    }
    {   // build A (gather rows, f32->bf16)
        int row = tid >> 3, sub = tid & 7;
        int d = d0 + row;
        bool ok = (d < D);
        size_t base = ok ? (size_t)src_idx[d] * 128 : 0;
        float4 z = make_float4(0.f, 0.f, 0.f, 0.f);
        float4 f0 = ok ? *(const float4*)(src_feat + base + sub * 16)      : z;
        float4 f1 = ok ? *(const float4*)(src_feat + base + sub * 16 + 4)  : z;
        float4 f2 = ok ? *(const float4*)(src_feat + base + sub * 16 + 8)  : z;
        float4 f3 = ok ? *(const float4*)(src_feat + base + sub * 16 + 12) : z;
        *(v8s*)&A_s[row * QD_ASTR + sub * 16]     = cvt8(f0, f1);
        *(v8s*)&A_s[row * QD_ASTR + sub * 16 + 8] = cvt8(f2, f3);
    }
    __syncthreads();

    v4f acc[2][2];
    #pragma unroll
    for (int mf = 0; mf < 2; ++mf)
        #pragma unroll
        for (int nf = 0; nf < 2; ++nf) acc[mf][nf] = (v4f)(0.f);

    #pragma unroll
    for (int ch = 0; ch < 4; ++ch) {
        v8s af[2], bf[2];
        #pragma unroll
        for (int mf = 0; mf < 2; ++mf)
            af[mf] = *(const v8s*)&A_s[(mf * 16 + l15) * QD_ASTR + ch * 32 + quad * 8];
        #pragma unroll
        for (int nf = 0; nf < 2; ++nf)
            bf[nf] = *(const v8s*)&B_s[(wn + nf * 16 + l15) * QD_BSTR + ch * 32 + quad * 8];
        #pragma unroll
        for (int mf = 0; mf < 2; ++mf)
            #pragma unroll
            for (int nf = 0; nf < 2; ++nf)
                acc[mf][nf] = __builtin_amdgcn_mfma_f32_16x16x32_bf16(
                                  af[mf], bf[nf], acc[mf][nf], 0, 0, 0);
    }
    #pragma unroll
    for (int nf = 0; nf < 2; ++nf) {
        int n = wn + nf * 16 + l15;
        float b = cq[n];
        #pragma unroll
        for (int mf = 0; mf < 2; ++mf)
            #pragma unroll
            for (int r = 0; r < 4; ++r) {
                int d = d0 + mf * 16 + quad * 4 + r;
                if (d < D) Qd[(size_t)d * 128 + n] = acc[mf][nf][r] + b;
            }
    }
}

// ---- KV GEMM: LDS-only inner loop, register-prefetched B staging ----
__global__ __launch_bounds__(256) void kv_mfma(
        const float* __restrict__ src_feat, const int* __restrict__ src_idx,
        const float* __restrict__ edge_f, const float* __restrict__ edge_dt,
        const float* __restrict__ time_w, const float* __restrict__ time_b,
        const unsigned short* __restrict__ Wt2,
        const float* __restrict__ wk_b, const float* __restrict__ wv_b,
        unsigned short* __restrict__ KVb, int D, int E) {
    __shared__ unsigned short A_s[BM * A_STRIDE];   // 25088 B
    __shared__ unsigned short B_s[NB * BSTR];       // 18432 B
    int tid = threadIdx.x;
    int e0 = blockIdx.x * BM;
    int lane = tid & 63, wave = tid >> 6;
    int l15 = lane & 15, quad = lane >> 4;
    int wn = wave * 64;
    int srow = tid >> 2, ssub = tid & 3;
    const unsigned short* wsrc = Wt2 + (size_t)srow * KPAD + ssub * 8;

    // prefetch B chunk 0 (issue before A-build so L2 latency overlaps VALU)
    v8s breg[4];
    #pragma unroll
    for (int j = 0; j < 4; ++j)
        breg[j] = *(const v8s*)(wsrc + (size_t)j * 64 * KPAD);

    // ---- build A tile ----
    {
        int row = tid >> 3, cb = (tid & 7) * 4;
        int e = e0 + row;
        bool ok = (e < E);
        size_t nbase = ok ? (size_t)src_idx[D + e] * 128 : 0;
        float4 z = make_float4(0.f, 0.f, 0.f, 0.f);
        #pragma unroll
        for (int i = 0; i < 4; i += 2) {
            float4 a = ok ? *(const float4*)(src_feat + nbase + (cb + i) * 4)     : z;
            float4 b = ok ? *(const float4*)(src_feat + nbase + (cb + i + 1) * 4) : z;
            *(v8s*)&A_s[row * A_STRIDE + (cb + i) * 4] = cvt8(a, b);
        }
        #pragma unroll
        for (int i = 0; i < 4; i += 2) {
            float4 a = ok ? *(const float4*)(edge_f + (size_t)e * 128 + (cb + i) * 4)     : z;
            float4 b = ok ? *(const float4*)(edge_f + (size_t)e * 128 + (cb + i + 1) * 4) : z;
            *(v8s*)&A_s[row * A_STRIDE + 128 + (cb + i) * 4] = cvt8(a, b);
        }
    }
    {   // time cols 256..383
        int c = tid & 127;
        int rbase = tid >> 7;
        bool vc = (c < DIM_TIME);
        float tw = vc ? time_w[c] : 0.f;
        float tb = vc ? time_b[c] : 0.f;
        #pragma unroll
        for (int i = 0; i < 16; ++i) {
            int row = i * 2 + rbase;
            int e = e0 + row;
            float v = 0.f;
            if (vc && e < E) v = __cosf(edge_dt[e] * tw + tb);
            A_s[row * A_STRIDE + 256 + c] = bf16_bits(v);
        }
    }
    __syncthreads();                       // A_s ready
    #pragma unroll
    for (int j = 0; j < 4; ++j)
        *(v8s*)&B_s[(srow + j * 64) * BSTR + ssub * 8] = breg[j];
    #pragma unroll
    for (int j = 0; j < 4; ++j)            // prefetch chunk 1
        breg[j] = *(const v8s*)(wsrc + (size_t)j * 64 * KPAD + BK);
    __syncthreads();                       // B_s(0) visible

    v4f acc[2][4];
    #pragma unroll
    for (int mf = 0; mf < 2; ++mf)
        #pragma unroll
        for (int nf = 0; nf < 4; ++nf) acc[mf][nf] = (v4f)(0.f);

    for (int ch = 0; ch < NCHUNK; ++ch) {
        v8s af[2], bf[4];
        #pragma unroll
        for (int mf = 0; mf < 2; ++mf)
            af[mf] = *(const v8s*)&A_s[(mf * 16 + l15) * A_STRIDE + ch * BK + quad * 8];
        #pragma unroll
        for (int nf = 0; nf < 4; ++nf)
            bf[nf] = *(const v8s*)&B_s[(wn + nf * 16 + l15) * BSTR + quad * 8];
        #pragma unroll
        for (int mf = 0; mf < 2; ++mf)
            #pragma unroll
            for (int nf = 0; nf < 4; ++nf)
                acc[mf][nf] = __builtin_amdgcn_mfma_f32_16x16x32_bf16(
                                  af[mf], bf[nf], acc[mf][nf], 0, 0, 0);
        if (ch + 1 < NCHUNK) {
            __syncthreads();               // all waves done reading B_s(ch)
            #pragma unroll
            for (int j = 0; j < 4; ++j)
                *(v8s*)&B_s[(srow + j * 64) * BSTR + ssub * 8] = breg[j];
            if (ch + 2 < NCHUNK) {
                #pragma unroll
                for (int j = 0; j < 4; ++j)
                    breg[j] = *(const v8s*)(wsrc + (size_t)j * 64 * KPAD + (ch + 2) * BK);
            }
            __syncthreads();               // B_s(ch+1) visible
        }
    }

    // ---- epilogue: pair-interleaved K/V layout, LDS-staged, linear stores ----
    __syncthreads();
    #pragma unroll
    for (int nf = 0; nf < 4; ++nf) {
        int n = wn + nf * 16 + l15;
        float bias; int slot;
        if (n < 128) { bias = wk_b[n]; slot = 2 * n - (n & 1); }
        else { int m = n - 128; bias = wv_b[m]; slot = 2 * m + 2 - (m & 1); }
        #pragma unroll
        for (int mf = 0; mf < 2; ++mf)
            #pragma unroll
            for (int r = 0; r < 4; ++r)
                A_s[(mf * 16 + quad * 4 + r) * C_STRIDE + slot] =
                    bf16_bits(acc[mf][nf][r] + bias);
    }
    __syncthreads();
    #pragma unroll
    for (int j = 0; j < 4; ++j) {
        int c = j * 256 + tid;
        int row = c >> 5;
        int col = (c & 31) * 8;
        if (e0 + row < E) {
            v8s v = *(const v8s*)&A_s[row * C_STRIDE + col];
            *(v8s*)&KVb[(size_t)(e0 + row) * NB + col] = v;
        }
    }
}

// ---- segment offsets (edge_dst sorted) ----
__global__ void seg_offsets(const int* __restrict__ edge_dst, int* __restrict__ start,
                            int D, int E) {
    int d = blockIdx.x * blockDim.x + threadIdx.x;
    if (d > D) return;
    int lo = 0, hi = E;
    while (lo < hi) {
        int mid = (lo + hi) >> 1;
        if (edge_dst[mid] < d) lo = mid + 1; else hi = mid;
    }
    start[d] = lo;
}

// ---- attention: 2 dsts/wave, interleaved KV (1x 8B load/edge), strip-8 ----
__global__ __launch_bounds__(256) void attn_kernel(
        const float* __restrict__ Qd, const unsigned short* __restrict__ KVb,
        const int* __restrict__ start, float* __restrict__ h, int D) {
    int lane = threadIdx.x & 63, wave = threadIdx.x >> 6;
    int dbase = blockIdx.x * 8 + wave * 2;
    #pragma unroll
    for (int i = 0; i < 2; ++i) {
        int d = dbase + i;
        if (d >= D) continue;
        float2 q = *(const float2*)(Qd + (size_t)d * 128 + lane * 2);
        int s0 = start[d], s1 = start[d + 1];
        float m = -INFINITY, l = 0.f, a0 = 0.f, a1 = 0.f;
        for (int e = s0; e < s1; e += 8) {
            int n = s1 - e; if (n > 8) n = 8;
            uint2 w8[8];
            #pragma unroll
            for (int j = 0; j < 8; ++j) {
                int idx = e + j; if (idx >= s1) idx = s1 - 1;
                w8[j] = *(const uint2*)(KVb + (size_t)idx * 256 + lane * 4);
            }
            for (int j = 0; j < n; ++j) {
                uint32_t ku = w8[j].x, vu = w8[j].y;
                float qk = q.x * bf16_lo(ku) + q.y * bf16_hi(ku);
                qk += __shfl_xor(qk, 4, 8);
                qk += __shfl_xor(qk, 2, 8);
                qk += __shfl_xor(qk, 1, 8);
                float s = qk > 0.f ? qk : 0.2f * qk;   // leaky_relu(., 0.2)
                float nm = fmaxf(m, s);
                float sc = __expf(m - nm);
                float p  = __expf(s - nm);
                l  = l  * sc + p;
                a0 = a0 * sc + p * bf16_lo(vu);
                a1 = a1 * sc + p * bf16_hi(vu);
                m = nm;
            }
        }
        float inv = (l > 0.f) ? 1.f / l : 0.f;
        *(float2*)(h + (size_t)d * 128 + lane * 2) = make_float2(a0 * inv, a1 * inv);
    }
}

// ---- out via MFMA + fused relu/LN. C-tile 32x128, K=256 (8 chunks) ----
__global__ __launch_bounds__(256) void out_mfma(
        const float* __restrict__ h, const float* __restrict__ src_feat,
        const int* __restrict__ src_idx, const unsigned short* __restrict__ Wob,
        const float* __restrict__ wout_b, const float* __restrict__ ln_g,
        const float* __restrict__ ln_b, float* __restrict__ out, int D) {
    __shared__ unsigned short A_s[32 * OUT_ASTR];   // 16896 B
    __shared__ unsigned short B_s[128 * BSTR];      // 9216 B
    __shared__ float C_s[32 * OUT_CSTR];            // 16896 B
    int tid = threadIdx.x;
    int lane = tid & 63, wave = tid >> 6;
    int l15 = lane & 15, quad = lane >> 4;
    int wn = wave * 32;
    int d0 = blockIdx.x * 32;
    int srow = tid >> 2, ssub = tid & 3;            // 64 rows/round, 2 rounds
    const unsigned short* wsrc = Wob + (size_t)srow * 256 + ssub * 8;

    v8s breg[2];
    #pragma unroll
    for (int j = 0; j < 2; ++j)
        breg[j] = *(const v8s*)(wsrc + (size_t)j * 64 * 256);

    {   // build A = [h | q_data] bf16
        int row = tid >> 3, sub = tid & 7;
        int d = d0 + row;
        bool ok = (d < D);
        const float* src = (sub < 4) ? (ok ? h + (size_t)d * 128 + sub * 32 : h)
                                     : (ok ? src_feat + (size_t)src_idx[d] * 128 + (sub - 4) * 32
                                           : src_feat);
        float4 z = make_float4(0.f, 0.f, 0.f, 0.f);
        float4 f0 = ok ? *(const float4*)(src)      : z;
        float4 f1 = ok ? *(const float4*)(src + 4)  : z;
        float4 f2 = ok ? *(const float4*)(src + 8)  : z;
        float4 f3 = ok ? *(const float4*)(src + 12) : z;
        float4 f4 = ok ? *(const float4*)(src + 16) : z;
        float4 f5 = ok ? *(const float4*)(src + 20) : z;
        float4 f6 = ok ? *(const float4*)(src + 24) : z;
        float4 f7 = ok ? *(const float4*)(src + 28) : z;
        *(v8s*)&A_s[row * OUT_ASTR + sub * 32]      = cvt8(f0, f1);
        *(v8s*)&A_s[row * OUT_ASTR + sub * 32 + 8]  = cvt8(f2, f3);
        *(v8s*)&A_s[row * OUT_ASTR + sub * 32 + 16] = cvt8(f4, f5);
        *(v8s*)&A_s[row * OUT_ASTR + sub * 32 + 24] = cvt8(f6, f7);
    }
    __syncthreads();
    #pragma unroll
    for (int j = 0; j < 2; ++j)
        *(v8s*)&B_s[(srow + j * 64) * BSTR + ssub * 8] = breg[j];
    #pragma unroll
    for (int j = 0; j < 2; ++j)
        breg[j] = *(const v8s*)(wsrc + (size_t)j * 64 * 256 + BK);
    __syncthreads();

    v4f acc[2][2];
    #pragma unroll
    for (int mf = 0; mf < 2; ++mf)
        #pragma unroll
        for (int nf = 0; nf < 2; ++nf) acc[mf][nf] = (v4f)(0.f);

    for (int ch = 0; ch < 8; ++ch) {
        v8s af[2], bf[2];
        #pragma unroll
        for (int mf = 0; mf < 2; ++mf)
            af[mf] = *(const v8s*)&A_s[(mf * 16 + l15) * OUT_ASTR + ch * BK + quad * 8];
        #pragma unroll
        for (int nf = 0; nf < 2; ++nf)
            bf[nf] = *(const v8s*)&B_s[(wn + nf * 16 + l15) * BSTR + quad * 8];
        #pragma unroll
        for (int mf = 0; mf < 2; ++mf)
            #pragma unroll
            for (int nf = 0; nf < 2; ++nf)
                acc[mf][nf] = __builtin_amdgcn_mfma_f32_16x16x32_bf16(
                                  af[mf], bf[nf], acc[mf][nf], 0, 0, 0);
        if (ch + 1 < 8) {
            __syncthreads();
            #pragma unroll
            for (int j = 0; j < 2; ++j)
                *(v8s*)&B_s[(srow + j * 64) * BSTR + ssub * 8] = breg[j];
            if (ch + 2 < 8) {
                #pragma unroll
                for (int j = 0; j < 2; ++j)
                    breg[j] = *(const v8s*)(wsrc + (size_t)j * 64 * 256 + (ch + 2) * BK);
            }
            __syncthreads();
        }
    }

    // stage relu(C + bias) to C_s
    __syncthreads();
    #pragma unroll
    for (int nf = 0; nf < 2; ++nf) {
        int n = wn + nf * 16 + l15;
        float b = wout_b[n];
        #pragma unroll
        for (int mf = 0; mf < 2; ++mf)
            #pragma unroll
            for (int r = 0; r < 4; ++r)
                C_s[(mf * 16 + quad * 4 + r) * OUT_CSTR + n] =
                    fmaxf(acc[mf][nf][r] + b, 0.f);
    }
    __syncthreads();

    // LN: 8 threads per row, 16 elems each
    {
        int row = tid >> 3, s = tid & 7;
        const float* cr = C_s + row * OUT_CSTR + s * 16;
        float4 x0 = *(const float4*)(cr);
        float4 x1 = *(const float4*)(cr + 4);
        float4 x2 = *(const float4*)(cr + 8);
        float4 x3 = *(const float4*)(cr + 12);
        float s1 = x0.x+x0.y+x0.z+x0.w + x1.x+x1.y+x1.z+x1.w
                 + x2.x+x2.y+x2.z+x2.w + x3.x+x3.y+x3.z+x3.w;
        float s2 = x0.x*x0.x+x0.y*x0.y+x0.z*x0.z+x0.w*x0.w
                 + x1.x*x1.x+x1.y*x1.y+x1.z*x1.z+x1.w*x1.w
                 + x2.x*x2.x+x2.y*x2.y+x2.z*x2.z+x2.w*x2.w
                 + x3.x*x3.x+x3.y*x3.y+x3.z*x3.z+x3.w*x3.w;
        s1 += __shfl_xor(s1, 4, 8); s2 += __shfl_xor(s2, 4, 8);
        s1 += __shfl_xor(s1, 2, 8); s2 += __shfl_xor(s2, 2, 8);
        s1 += __shfl_xor(s1, 1, 8); s2 += __shfl_xor(s2, 1, 8);
        float mu  = s1 * (1.f / 128.f);
        float var = s2 * (1.f / 128.f) - mu * mu;
        float rs  = rsqrtf(var + 1e-5f);
        int d = d0 + row;
        if (d < D) {
            float4 g0 = *(const float4*)(ln_g + s * 16);
            float4 g1 = *(const float4*)(ln_g + s * 16 + 4);
            float4 g2 = *(const float4*)(ln_g + s * 16 + 8);
            float4 g3 = *(const float4*)(ln_g + s * 16 + 12);
            float4 b0 = *(const float4*)(ln_b + s * 16);
            float4 b1 = *(const float4*)(ln_b + s * 16 + 4);
            float4 b2 = *(const float4*)(ln_b + s * 16 + 8);
            float4 b3 = *(const float4*)(ln_b + s * 16 + 12);
            float* op = out + (size_t)d * 128 + s * 16;
            float4 o0 = make_float4((x0.x-mu)*rs*g0.x+b0.x, (x0.y-mu)*rs*g0.y+b0.y,
                                    (x0.z-mu)*rs*g0.z+b0.z, (x0.w-mu)*rs*g0.w+b0.w);
            float4 o1 = make_float4((x1.x-mu)*rs*g1.x+b1.x, (x1.y-mu)*rs*g1.y+b1.y,
                                    (x1.z-mu)*rs*g1.z+b1.z, (x1.w-mu)*rs*g1.w+b1.w);
            float4 o2 = make_float4((x2.x-mu)*rs*g2.x+b2.x, (x2.y-mu)*rs*g2.y+b2.y,
                                    (x2.z-mu)*rs*g2.z+b2.z, (x2.w-mu)*rs*g2.w+b2.w);
            float4 o3 = make_float4((x3.x-mu)*rs*g3.x+b3.x, (x3.y-mu)*rs*g3.y+b3.y,
                                    (x3.z-mu)*rs*g3.z+b3.z, (x3.w-mu)*rs*g3.w+b3.w);
            *(float4*)(op)      = o0;
            *(float4*)(op + 4)  = o1;
            *(float4*)(op + 8)  = o2;
            *(float4*)(op + 12) = o3;
        }
    }
}

extern "C" void kernel_launch(void* const* d_in, const int* in_sizes, int n_in,
                              void* d_out, int out_size, void* d_ws, size_t ws_size,
                              hipStream_t stream) {
    const float* src_feat = (const float*)d_in[0];
    const float* edge_f   = (const float*)d_in[1];
    const float* edge_dt  = (const float*)d_in[2];
    const float* time_w   = (const float*)d_in[3];
    const float* time_b   = (const float*)d_in[4];
    const float* wq_w     = (const float*)d_in[5];
    const float* wq_b     = (const float*)d_in[6];
    const float* wk_w     = (const float*)d_in[7];
    const float* wk_b     = (const float*)d_in[8];
    const float* wv_w     = (const float*)d_in[9];
    const float* wv_b     = (const float*)d_in[10];
    const float* wout_w   = (const float*)d_in[11];
    const float* wout_b   = (const float*)d_in[12];
    const float* ln_g     = (const float*)d_in[13];
    const float* ln_b     = (const float*)d_in[14];
    const int*   src_idx  = (const int*)d_in[15];
    const int*   edge_dst = (const int*)d_in[16];

    int DE = in_sizes[0] / 128;
    int E  = in_sizes[1] / 128;
    int D  = DE - E;

    char* ws = (char*)d_ws;
    size_t off = 0;
    auto alloc = [&](size_t bytes) {
        void* p = ws + off;
        off = (off + bytes + 511) & ~(size_t)511;
        return p;
    };
    unsigned short* Wt2   = (unsigned short*)alloc((size_t)NB * KPAD * 2);
    unsigned short* Wqb   = (unsigned short*)alloc(128 * 128 * 2);
    unsigned short* Wob   = (unsigned short*)alloc(128 * 256 * 2);
    float*          cq    = (float*)alloc(128 * 4);
    float*          Qd    = (float*)alloc((size_t)D * 128 * 4);
    unsigned short* KVb   = (unsigned short*)alloc((size_t)E * 256 * 2);
    float*          hb    = (float*)alloc((size_t)D * 128 * 4);
    int*            start = (int*)alloc((size_t)(D + 1) * 4);

    hipLaunchKernelGGL(prep_wt2, dim3(NB), dim3(KPAD), 0, stream, wk_w, wv_w, Wt2);
    hipLaunchKernelGGL(prep_wqb, dim3(128), dim3(128), 0, stream, wq_w, Wqb);
    hipLaunchKernelGGL(prep_wob, dim3(128), dim3(256), 0, stream, wout_w, Wob);
    hipLaunchKernelGGL(prep_cq, dim3(1), dim3(128), 0, stream, wq_w, wq_b, time_b, cq);
    hipLaunchKernelGGL(qd_mfma, dim3((D + 31) / 32), dim3(256), 0, stream,
                       src_feat, src_idx, Wqb, cq, Qd, D);
    hipLaunchKernelGGL(kv_mfma, dim3((E + BM - 1) / BM), dim3(256), 0, stream,
                       src_feat, src_idx, edge_f, edge_dt, time_w, time_b,
                       Wt2, wk_b, wv_b, KVb, D, E);
    hipLaunchKernelGGL(seg_offsets, dim3((D + 1 + 255) / 256), dim3(256), 0, stream,
                       edge_dst, start, D, E);
    hipLaunchKernelGGL(attn_kernel, dim3((D + 7) / 8), dim3(256), 0, stream,
                       Qd, KVb, start, hb, D);
    hipLaunchKernelGGL(out_mfma, dim3((D + 31) / 32), dim3(256), 0, stream,
                       hb, src_feat, src_idx, Wob, wout_b, ln_g, ln_b, (float*)d_out, D);
}